// Round 10
// baseline (171.991 us; speedup 1.0000x reference)
//
#include <hip/hip_runtime.h>
#include <hip/hip_bf16.h>
#include <stdint.h>

// FP8QDQLinear: out[m,o] = 4 * (q_in @ q_w^T) + bias, q_* exact e4m3 values.
// R10: R9's verified X/Y counted-vmcnt schedule, re-hosted on a 128^2 tile
// with 4 waves + 64 KiB LDS -> 2 blocks/CU = TWO independent barrier domains
// per CU (R9 diagnosis: 256^2 = one domain -> every wait idles all 4 SIMDs;
// matrix pipe idle 73%). Per-wave LDS reads at the 16-b128/K-tile minimum.
// Ledger (unchanged from R9): entering Y(k) 8 in flight {B(k+1),A(k+1)};
// +B(k+2) = 12; VMW(4) drains exactly B(k+1)+A(k+1) (read at X(k+1), after
// the BAR); A(k+2) staged post-BAR. Every overwrite is >=1 barrier after the
// last ds_read-issue of its target. Never vmcnt(0) in the loop.
// MX-fp8 16x16x128, unit E8M0 scales = exact e4m3 math. LDS column-chunk
// layout (slot = col16*128 + row), conflict-free (verified 0 since R3).

typedef __attribute__((ext_vector_type(4))) float f32x4;
typedef __attribute__((ext_vector_type(2))) int i32x2;
typedef __attribute__((ext_vector_type(4))) int i32x4;
typedef __attribute__((ext_vector_type(8))) int i32x8;

#define FP8_MAX 448.0f
#define UNIT_SCALE 0x7F7F7F7F  // E8M0 127 = 2^0 in every byte

// ---------------- quantization pass: f32 -> e4m3fn bytes ----------------
__global__ void quant_fp8_kernel(const float* __restrict__ x,
                                 uint32_t* __restrict__ q,
                                 float mul, int n8) {
    int i = blockIdx.x * blockDim.x + threadIdx.x;
    if (i >= n8) return;
    const float4* xv = (const float4*)x;
    float4 v0 = xv[2 * i];
    float4 v1 = xv[2 * i + 1];
    float a[8] = {v0.x, v0.y, v0.z, v0.w, v1.x, v1.y, v1.z, v1.w};
#pragma unroll
    for (int j = 0; j < 8; ++j) {
        float t = a[j] * mul;
        t = fminf(fmaxf(t, -FP8_MAX), FP8_MAX);
        a[j] = t;
    }
    int lo = 0, hi = 0;
    lo = __builtin_amdgcn_cvt_pk_fp8_f32(a[0], a[1], lo, false);
    lo = __builtin_amdgcn_cvt_pk_fp8_f32(a[2], a[3], lo, true);
    hi = __builtin_amdgcn_cvt_pk_fp8_f32(a[4], a[5], hi, false);
    hi = __builtin_amdgcn_cvt_pk_fp8_f32(a[6], a[7], hi, true);
    i32x2 out;
    out.x = lo;
    out.y = hi;
    ((i32x2*)q)[i] = out;
}

// ---------------- MX-fp8 GEMM: C = 4*(A_q @ W_q^T) + bias ----------------
#define KTILES 32  // K / 128

__device__ static inline void gload_lds16(const void* g, void* l) {
    __builtin_amdgcn_global_load_lds(
        (const __attribute__((address_space(1))) void*)g,
        (__attribute__((address_space(3))) void*)l, 16, 0, 0);
}

// stage a full 16 KB operand K-tile: 4 calls x (256 thr x 16B)
#define STAGE_FULL(GSRC, KB, LBASE)                                        \
    gload_lds16((GSRC) + (KB),       (LBASE) + t * 16);                    \
    gload_lds16((GSRC) + (KB) + 32,  (LBASE) + 4096  + t * 16);            \
    gload_lds16((GSRC) + (KB) + 64,  (LBASE) + 8192  + t * 16);            \
    gload_lds16((GSRC) + (KB) + 96,  (LBASE) + 12288 + t * 16);

#define READ_A(LBASE, MH)                                                  \
    _Pragma("unroll") for (int m = 0; m < 2; ++m) {                        \
        i32x4 lo = *(const i32x4*)((LBASE) + aoff + (MH) * 512 + m * 256);        \
        i32x4 hi = *(const i32x4*)((LBASE) + aoff + (MH) * 512 + m * 256 + 2048); \
        areg[m] = (i32x8){lo[0], lo[1], lo[2], lo[3], hi[0], hi[1], hi[2], hi[3]};\
    }

#define READ_B_ALL(LBASE)                                                  \
    _Pragma("unroll") for (int n = 0; n < 4; ++n) {                        \
        i32x4 lo = *(const i32x4*)((LBASE) + boff + n * 256);                     \
        i32x4 hi = *(const i32x4*)((LBASE) + boff + n * 256 + 2048);              \
        breg[n] = (i32x8){lo[0], lo[1], lo[2], lo[3], hi[0], hi[1], hi[2], hi[3]};\
    }

#define MFMA8(MH)                                                          \
    __builtin_amdgcn_s_setprio(1);                                         \
    _Pragma("unroll") for (int m = 0; m < 2; ++m)                          \
        _Pragma("unroll") for (int n = 0; n < 4; ++n)                      \
            acc[(MH) * 2 + m][n] =                                         \
                __builtin_amdgcn_mfma_scale_f32_16x16x128_f8f6f4(          \
                    areg[m], breg[n], acc[(MH) * 2 + m][n],                \
                    0, 0, 0, UNIT_SCALE, 0, UNIT_SCALE);                   \
    __builtin_amdgcn_s_setprio(0);

#define BAR() __builtin_amdgcn_s_barrier()
#define VMW(N) asm volatile("s_waitcnt vmcnt(" #N ")" ::: "memory")

__global__ __launch_bounds__(256, 2) void fp8_gemm_bias_kernel(
        const uint8_t* __restrict__ Aq, const uint8_t* __restrict__ Wq,
        const float* __restrict__ bias, float* __restrict__ C,
        int M, int N, int K) {
    // layout: [A0 | B0 | A1 | B1], each 16 KiB; computed offsets only.
    __shared__ __align__(16) uint8_t lds[65536];

    const int t = threadIdx.x;
    const int lane = t & 63;
    const int w = t >> 6;       // wave 0..3
    const int wr = w >> 1;      // wave row 0..1  (64 rows each)
    const int wc = w & 1;       // wave col 0..1  (64 cols each)
    const int lr = lane & 15;
    const int lk = lane >> 4;   // K-group (32 bytes)

    // XCD-aware swizzle: 1024 blocks, 8 XCDs, 128 per XCD (bijective)
    const int bid = blockIdx.x;
    const int swz = (bid & 7) * 128 + (bid >> 3);
    const int bm = swz >> 5;    // 0..31
    const int bn = swz & 31;    // 0..31

    const uint8_t* Abase = Aq + (size_t)(bm * 128) * K;
    const uint8_t* Bbase = Wq + (size_t)(bn * 128) * K;

    // staging source: call c: row = t&127, col16 = 2c + (t>>7)
    const int srow = t & 127;
    const int scol = (t >> 7) * 16;
    const uint8_t* gA = Abase + (size_t)srow * K + scol;
    const uint8_t* gB = Bbase + (size_t)srow * K + scol;

    // fragment read bases: row = wr*64 + f*16 + lr, col16 pair (2lk, 2lk+1);
    // col16 stride = 128 rows * 16B = 2048 B
    const int aoff = lk * 4096 + wr * 1024 + lr * 16;
    const int boff = lk * 4096 + wc * 1024 + lr * 16;

    f32x4 acc[4][4];
#pragma unroll
    for (int mi = 0; mi < 4; ++mi)
#pragma unroll
        for (int ni = 0; ni < 4; ++ni)
            acc[mi][ni] = (f32x4){0.f, 0.f, 0.f, 0.f};

    i32x8 areg[2], breg[4];

    // ---- prologue: A(0),B(0)->buf0; B(1),A(1)->buf1 (B1,A1 stay in flight) ----
    STAGE_FULL(gA, 0, lds)                  // A(0) -> sA0
    STAGE_FULL(gB, 0, lds + 16384)          // B(0) -> sB0
    STAGE_FULL(gB, 128, lds + 49152)        // B(1) -> sB1
    STAGE_FULL(gA, 128, lds + 32768)        // A(1) -> sA1
    VMW(8);   // 16 outstanding -> drain oldest 8 = A(0)+B(0); B(1),A(1) fly
    BAR();

    for (int k = 0; k < KTILES; ++k) {
        const int co = (k & 1) << 15;       // current buffer byte offset
        uint8_t* const sAc = lds + co;
        uint8_t* const sBc = lds + 16384 + co;
        const int kbN = ((k + 2) & 31) * 128;  // tile k+2 (wraps at tail)

        // ---- phase X: all B frags + A mh0 ----
        READ_A(sAc, 0)
        READ_B_ALL(sBc)
        BAR();
        MFMA8(0)

        // ---- phase Y: A mh1; stage B(k+2)->sB(cur); counted drain;
        //      post-BAR stage A(k+2)->sA(cur) ----
        READ_A(sAc, 1)
        STAGE_FULL(gB, kbN, sBc)
        VMW(4);   // 12 outstanding -> drains B(k+1)+A(k+1); B(k+2) flies
        BAR();
        STAGE_FULL(gA, kbN, sAc)
        MFMA8(1)
    }

    VMW(0);  // drain wrap-tail stages before endpgm (epilogue has no LDS use)

    // ---- epilogue: C/D layout col=lane&15, row=(lane>>4)*4+j ----
    const int crow0 = bm * 128 + wr * 64 + lk * 4;
    const int ccol0 = bn * 128 + wc * 64 + lr;
#pragma unroll
    for (int ni = 0; ni < 4; ++ni) {
        const int col = ccol0 + ni * 16;
        const float bv = bias[col];
#pragma unroll
        for (int mi = 0; mi < 4; ++mi) {
            const int row = crow0 + mi * 16;
#pragma unroll
            for (int j = 0; j < 4; ++j) {
                C[(size_t)(row + j) * N + col] = acc[mi][ni][j] * 4.0f + bv;
            }
        }
    }
}

extern "C" void kernel_launch(void* const* d_in, const int* in_sizes, int n_in,
                              void* d_out, int out_size, void* d_ws, size_t ws_size,
                              hipStream_t stream) {
    const int M = 4096, N = 4096, K = 4096;
    const float* input  = (const float*)d_in[0];   // [M][K] f32
    const float* weight = (const float*)d_in[1];   // [N][K] f32 (e4m3-grid values)
    const float* bias   = (const float*)d_in[2];   // [N] f32
    float* out = (float*)d_out;                    // [M][N] f32

    uint8_t* Aq = (uint8_t*)d_ws;                        // 16 MiB
    uint8_t* Wq = (uint8_t*)d_ws + (size_t)M * K;        // 16 MiB

    {
        int n8 = (M * K) / 8;
        int blocks = (n8 + 255) / 256;
        quant_fp8_kernel<<<blocks, 256, 0, stream>>>(input, (uint32_t*)Aq, 0.5f, n8);
        quant_fp8_kernel<<<blocks, 256, 0, stream>>>(weight, (uint32_t*)Wq, 1.0f, n8);
    }

    dim3 grid(1024);  // (M/128) x (N/128), XCD-swizzled in-kernel
    fp8_gemm_bias_kernel<<<grid, 256, 0, stream>>>(Aq, Wq, bias, out, M, N, K);
}